// Round 6
// baseline (233.075 us; speedup 1.0000x reference)
//
#include <hip/hip_runtime.h>
#include <hip/hip_bf16.h>

// Problem constants (B=4, S=2048, D=1024, fp32 in/out)
#define BB 4
#define SS 2048
#define DD 1024

using f32x4  = __attribute__((ext_vector_type(4))) float;
using f32x16 = __attribute__((ext_vector_type(16))) float;
using i32x4  = __attribute__((ext_vector_type(4))) int;
using i32x8  = __attribute__((ext_vector_type(8))) int;

struct f8_t { unsigned char b; };

// async global->LDS, 16B per lane. LDS dest = wave-uniform base + lane*16.
__device__ __forceinline__ void gld16(const void* g, void* l) {
    __builtin_amdgcn_global_load_lds(
        (const __attribute__((address_space(1))) void*)(g),
        (__attribute__((address_space(3))) void*)(l),
        16, 0, 0);
}

__device__ __forceinline__ void store1(float* p, float v) { *p = v; }
__device__ __forceinline__ void store1(f8_t* p, float v)  {
    p->b = (unsigned char)(__builtin_amdgcn_cvt_pk_fp8_f32(v, v, 0, false) & 0xff);
}

// ---------------------------------------------------------------------------
// FUSED: x fp32 -> fp8(e4m3)  AND  xsum[b][d] = sum_s x[b][s][d] (fp32 exact).
// Reads x ONCE (was read twice by separate cvt_x + xsum kernels).
// grid 256: block = (b, 32-row s-chunk); 256 thr = 2 row-groups x 128 d-groups
// of 8 consecutive d. Per-thread fp32 accumulate over 16 rows, LDS pairwise
// reduce across the 2 groups, then one atomicAdd per (d8-lane, j).
// ---------------------------------------------------------------------------
__global__ void cvt_x_xsum_kernel(const float* __restrict__ x,
                                  unsigned char* __restrict__ x8,
                                  float* __restrict__ xsum) {
    int b  = blockIdx.x >> 6;
    int s0 = (blockIdx.x & 63) * 32;
    int t  = threadIdx.x;
    int g  = t >> 7;                  // 0..1 : row group (16 rows each)
    int dt = t & 127;
    int d8 = dt * 8;
    const float* xb = x + ((size_t)b * SS + s0 + g * 16) * DD + d8;
    unsigned char* x8b = x8 + ((size_t)b * SS + s0 + g * 16) * DD + d8;

    float a0=0,a1=0,a2=0,a3=0,a4=0,a5=0,a6=0,a7=0;
#pragma unroll 4
    for (int i = 0; i < 16; ++i) {
        float4 u = *(const float4*)(xb + (size_t)i * DD);
        float4 v = *(const float4*)(xb + (size_t)i * DD + 4);
        int lo = __builtin_amdgcn_cvt_pk_fp8_f32(u.x, u.y, 0, false);
        lo     = __builtin_amdgcn_cvt_pk_fp8_f32(u.z, u.w, lo, true);
        int hi = __builtin_amdgcn_cvt_pk_fp8_f32(v.x, v.y, 0, false);
        hi     = __builtin_amdgcn_cvt_pk_fp8_f32(v.z, v.w, hi, true);
        *(int2*)(x8b + (size_t)i * DD) = make_int2(lo, hi);
        a0 += u.x; a1 += u.y; a2 += u.z; a3 += u.w;
        a4 += v.x; a5 += v.y; a6 += v.z; a7 += v.w;
    }
    __shared__ float red[2][128][8];
    float* r = red[g][dt];
    r[0]=a0; r[1]=a1; r[2]=a2; r[3]=a3; r[4]=a4; r[5]=a5; r[6]=a6; r[7]=a7;
    __syncthreads();
    if (t < 128) {
        float* p0 = red[0][t];
        float* p1 = red[1][t];
#pragma unroll
        for (int j = 0; j < 8; ++j)
            atomicAdd(&xsum[b * DD + t * 8 + j], p0[j] + p1[j]);
    }
}

// Wq,Wk,Wv -> fp8 contiguous. n8 = nw/8.
__global__ void cvt_w_kernel(const float* __restrict__ Wq, const float* __restrict__ Wk,
                             const float* __restrict__ Wv, unsigned char* __restrict__ w8, int n8) {
    int i = blockIdx.x * blockDim.x + threadIdx.x;
    int seg = i / n8;            // wave-uniform (n8 % 256 == 0)
    int j = i - seg * n8;
    const float* src = (seg == 0) ? Wq : (seg == 1) ? Wk : Wv;
    float4 a = ((const float4*)src)[2 * j];
    float4 b = ((const float4*)src)[2 * j + 1];
    int lo = __builtin_amdgcn_cvt_pk_fp8_f32(a.x, a.y, 0, false);
    lo     = __builtin_amdgcn_cvt_pk_fp8_f32(a.z, a.w, lo, true);
    int hi = __builtin_amdgcn_cvt_pk_fp8_f32(b.x, b.y, 0, false);
    hi     = __builtin_amdgcn_cvt_pk_fp8_f32(b.z, b.w, hi, true);
    ((int2*)(w8 + (size_t)seg * n8 * 8))[j] = make_int2(lo, hi);
}

// colsumV[b][c] = sum_d xsum[b][d] * Wv[c][d]   (one wave per output, exact
// fp32 -- the output's leading term colsumV/2048 flows through this)
__global__ void colsumv_kernel(const float* __restrict__ Wv, const float* __restrict__ xsum,
                               float* __restrict__ colsum) {
    int idx  = blockIdx.x * 4 + (threadIdx.x >> 6);   // 0..4095
    int b    = idx >> 10, c = idx & 1023;
    int lane = threadIdx.x & 63;
    const float* wr = Wv + (size_t)c * DD;
    const float* xs = xsum + b * DD;
    float acc = 0.f;
#pragma unroll 4
    for (int d = lane; d < DD; d += 64) acc += wr[d] * xs[d];
#pragma unroll
    for (int off = 32; off; off >>= 1) acc += __shfl_xor(acc, off);
    if (lane == 0) colsum[idx] = acc;
}

// ---------------------------------------------------------------------------
// fp8 (e4m3) NT GEMM via MX-scaled MFMA 32x32x64.
// 128x128 tile, BK=256 (A/B: r3's proven loop with HALF the K-tile count --
// per-tile fixed costs {stage-issue, vmcnt drain, 2 barriers, lgkm tails}
// are paid NT=4 times instead of 8; staged bytes unchanged).
// 256 threads (4 waves, 2x2), per-wave 64x64 out as 2x2 of 32x32 frags.
// LDS 64 KB -> 2 blocks/CU (occupancy proven irrelevant in r3-r5).
// XOR-8 LDS swizzle on the staging source (T2), 16 chunks of 16B per row.
// A/B frag layout (32x32x64 f8f6f4): row/col = lane&31, k-bytes =
//   (lane>>5)*32 + kstep*64. C/D: col = lane&31,
//   row = (reg&3) + 8*(reg>>2) + 4*(lane>>5), reg in [0,16).
// Epilogue modes:
//   0: plain store CT              (QK projection, fp8 out)
//   1: col-batch-split fp8 store   (V^T)
//   2: scores: t=exp(acc*qmask/32)-1; store fp8 512t; atomicAdd row sums of t
//   3: PV: out = (acc + colsumV[d]) / (2048 + rsum[q]), fp32; A-scale 2^-9
// ---------------------------------------------------------------------------
template <int MODE, typename CT>
__global__ __launch_bounds__(256, 2) void gemm_f8(
    const unsigned char* __restrict__ A, const unsigned char* __restrict__ B,
    CT* __restrict__ C, int M, int N, int K,
    long batchA, long batchB, long batchC,
    int ldc, int col_shift, long cstride,
    const float* __restrict__ qmask, float* __restrict__ rsum,
    const float* __restrict__ colsum) {
    constexpr int BM = 128, BN = 128, BK = 256;
    constexpr int SCALE_A = (MODE == 3) ? 118 : 127;   // 2^-9 un-scales T' = 512 t
    __shared__ __attribute__((aligned(16))) unsigned char As[BM * BK];  // 32 KB
    __shared__ __attribute__((aligned(16))) unsigned char Bs[BN * BK];  // 32 KB

    const int tid  = threadIdx.x;
    const int lane = tid & 63;
    const int wv   = tid >> 6;        // 0..3
    const int l31  = lane & 31;
    const int half = lane >> 5;       // 0..1
    const int hb   = half * 2;        // logical 16B-chunk base within a kstep
    const int wm   = wv >> 1;         // 0..1 : 64-row band
    const int wn   = wv & 1;          // 0..1 : 64-col band

    const int m0 = blockIdx.y * BM;
    const int n0 = blockIdx.x * BN;
    const long z = blockIdx.z;
    const unsigned char* Ab = A + z * batchA;
    const unsigned char* Bb = B + z * batchB;

    f32x16 acc[2][2] = {};

    // stage round j (j=0..7) of a 128x256-byte tile for K-offset kt.
    // 16 chunks of 16B per row; source carries the XOR-8 swizzle, LDS dest is
    // linear (global_load_lds writes wave-uniform base + lane*16).
#define STAGE(dst, src, kt, j) do {                                           \
        int slot_ = (j) * 256 + tid;                                          \
        int r_ = slot_ >> 4;                                                  \
        int c_ = (slot_ & 15) ^ (r_ & 7);                                     \
        gld16((src) + (size_t)r_ * K + ((kt) + c_ * 16),                      \
              (dst) + (size_t)((j) * 256 + wv * 64) * 16);                    \
    } while (0)
    // read one 32x64 fragment (32 B/lane, two swizzled 16B chunks), kstep s
#define RDFRAG(f, base, rr, s) do {                                           \
        int r_ = (rr);                                                        \
        int c0_ = (s) * 4 + hb;                                               \
        const unsigned char* rp_ = (base) + r_ * 256;                         \
        i32x4 q0_ = *(const i32x4*)(rp_ + ((c0_ ^ (r_ & 7)) * 16));           \
        i32x4 q1_ = *(const i32x4*)(rp_ + (((c0_ + 1) ^ (r_ & 7)) * 16));     \
        f[0]=q0_[0]; f[1]=q0_[1]; f[2]=q0_[2]; f[3]=q0_[3];                   \
        f[4]=q1_[0]; f[5]=q1_[1]; f[6]=q1_[2]; f[7]=q1_[3];                   \
    } while (0)
#define MFMA(d, a, b) \
        d = __builtin_amdgcn_mfma_scale_f32_32x32x64_f8f6f4(a, b, d, 0, 0, 0, SCALE_A, 0, 127)

    for (int kt = 0; kt < K; kt += BK) {
        const unsigned char* Asrc = Ab + (size_t)m0 * K;
        const unsigned char* Bsrc = Bb + (size_t)n0 * K;
        STAGE(As, Asrc, kt, 0); STAGE(As, Asrc, kt, 1);
        STAGE(As, Asrc, kt, 2); STAGE(As, Asrc, kt, 3);
        STAGE(As, Asrc, kt, 4); STAGE(As, Asrc, kt, 5);
        STAGE(As, Asrc, kt, 6); STAGE(As, Asrc, kt, 7);
        STAGE(Bs, Bsrc, kt, 0); STAGE(Bs, Bsrc, kt, 1);
        STAGE(Bs, Bsrc, kt, 2); STAGE(Bs, Bsrc, kt, 3);
        STAGE(Bs, Bsrc, kt, 4); STAGE(Bs, Bsrc, kt, 5);
        STAGE(Bs, Bsrc, kt, 6); STAGE(Bs, Bsrc, kt, 7);
        asm volatile("s_waitcnt vmcnt(0)" ::: "memory");
        __syncthreads();

#pragma unroll
        for (int s = 0; s < 4; ++s) {
            i32x8 a0, a1, b0, b1;
            RDFRAG(a0, As, wm * 64 +  0 + l31, s);
            RDFRAG(a1, As, wm * 64 + 32 + l31, s);
            RDFRAG(b0, Bs, wn * 64 +  0 + l31, s);
            RDFRAG(b1, Bs, wn * 64 + 32 + l31, s);
            MFMA(acc[0][0], a0, b0); MFMA(acc[0][1], a0, b1);
            MFMA(acc[1][0], a1, b0); MFMA(acc[1][1], a1, b1);
        }
        __syncthreads();
    }
#undef STAGE
#undef RDFRAG
#undef MFMA

    // ---- epilogue (C/D: col=lane&31, row=(reg&3)+8*(reg>>2)+4*half) --------
    CT* Cb = C + z * batchC;

    if constexpr (MODE == 0) {
#pragma unroll
        for (int mi = 0; mi < 2; ++mi)
#pragma unroll
            for (int ni = 0; ni < 2; ++ni) {
                int colg = n0 + wn * 64 + ni * 32 + l31;
#pragma unroll
                for (int reg = 0; reg < 16; ++reg) {
                    int rowg = m0 + wm * 64 + mi * 32 + (reg & 3) + 8 * (reg >> 2) + 4 * half;
                    store1(Cb + (size_t)rowg * ldc + colg, acc[mi][ni][reg]);
                }
            }
    } else if constexpr (MODE == 1) {
#pragma unroll
        for (int mi = 0; mi < 2; ++mi)
#pragma unroll
            for (int ni = 0; ni < 2; ++ni) {
                int colg = n0 + wn * 64 + ni * 32 + l31;
                int cb   = colg >> col_shift;
                int ccol = colg - (cb << col_shift);
#pragma unroll
                for (int reg = 0; reg < 16; ++reg) {
                    int rowg = m0 + wm * 64 + mi * 32 + (reg & 3) + 8 * (reg >> 2) + 4 * half;
                    store1(Cb + (long)cb * cstride + (size_t)rowg * ldc + ccol, acc[mi][ni][reg]);
                }
            }
    } else if constexpr (MODE == 2) {
        const float* qm = qmask + (z << 11);
        float* rs = rsum + (z << 11);
#pragma unroll
        for (int mi = 0; mi < 2; ++mi) {
#pragma unroll
            for (int reg = 0; reg < 16; ++reg) {
                int rowg = m0 + wm * 64 + mi * 32 + (reg & 3) + 8 * (reg >> 2) + 4 * half;
                float fac = qm[rowg] * 0.03125f;     // q_mask / sqrt(1024)
                float part = 0.f;
#pragma unroll
                for (int ni = 0; ni < 2; ++ni) {
                    int colg = n0 + wn * 64 + ni * 32 + l31;
                    float t = __expf(acc[mi][ni][reg] * fac) - 1.0f;
                    part += t;
                    store1(Cb + (size_t)rowg * ldc + colg, t * 512.0f);
                }
                // reduce over the 32 lanes of this half (they share rowg)
                part += __shfl_xor(part, 1);
                part += __shfl_xor(part, 2);
                part += __shfl_xor(part, 4);
                part += __shfl_xor(part, 8);
                part += __shfl_xor(part, 16);
                if (l31 == 0) atomicAdd(&rs[rowg], part);
            }
        }
    } else {  // MODE == 3
        const float* rs = rsum + (z << 11);
        const float* cs = colsum + (z << 10);
#pragma unroll
        for (int mi = 0; mi < 2; ++mi) {
#pragma unroll
            for (int reg = 0; reg < 16; ++reg) {
                int rowg = m0 + wm * 64 + mi * 32 + (reg & 3) + 8 * (reg >> 2) + 4 * half;
                float inv = 1.0f / (2048.0f + rs[rowg]);
#pragma unroll
                for (int ni = 0; ni < 2; ++ni) {
                    int colg = n0 + wn * 64 + ni * 32 + l31;
                    store1(Cb + (size_t)rowg * ldc + colg, (acc[mi][ni][reg] + cs[colg]) * inv);
                }
            }
        }
    }
}

// ---------------------------------------------------------------------------
extern "C" void kernel_launch(void* const* d_in, const int* in_sizes, int n_in,
                              void* d_out, int out_size, void* d_ws, size_t ws_size,
                              hipStream_t stream) {
    const float* x     = (const float*)d_in[0];
    const float* Wq    = (const float*)d_in[1];
    const float* Wk    = (const float*)d_in[2];
    const float* Wv    = (const float*)d_in[3];
    const float* qmask = (const float*)d_in[4];
    float* out = (float*)d_out;

    const long nx = (long)BB * SS * DD;   // 8,388,608
    const long nw = (long)DD * DD;        // 1,048,576

    unsigned char* ws  = (unsigned char*)d_ws;
    unsigned char* x8  = ws;                          // x fp8         8.4 MB
    unsigned char* w8  = x8 + nx;                     // Wq,Wk,Wv fp8  3 MB
    unsigned char* qk8 = w8 + 3 * nw;                 // Q,K fp8       16.8 MB
    unsigned char* vt8 = qk8 + 2 * nx;                // V^T fp8 (B,D,S) 8.4 MB
    unsigned char* t8  = vt8 + nx;                    // T = 512(exp-1) fp8 (B,S,S) 16.8 MB
    float* xsum   = (float*)(t8 + (long)BB * SS * SS);// (B,D) 16 KB
    float* rs     = xsum + BB * DD;                   // (B,S) 32 KB  (Σt per row)
    float* colsum = rs + BB * SS;                     // (B,D) 16 KB  (exact)

    // 0. zero the atomic accumulators (xsum and rs are adjacent)
    hipMemsetAsync(xsum, 0, (size_t)(BB * DD + BB * SS) * sizeof(float), stream);

    // 1. fused convert+xsum (reads x once), W convert, exact colsumV
    cvt_x_xsum_kernel<<<dim3(256), dim3(256), 0, stream>>>(x, x8, xsum);
    cvt_w_kernel<<<dim3((int)(3 * nw / 8 / 256)), dim3(256), 0, stream>>>(Wq, Wk, Wv, w8, (int)(nw / 8));
    colsumv_kernel<<<dim3(1024), dim3(256), 0, stream>>>(Wv, xsum, colsum);

    // 2. Q = x@Wq^T, K = x@Wk^T  (fp8 MX GEMM, z=2, fp8 out)  grid 8x64x2
    gemm_f8<0, f8_t><<<dim3(DD / 128, (BB * SS) / 128, 2), 256, 0, stream>>>(
        x8, w8, (f8_t*)qk8, BB * SS, DD, DD, 0, nw, nx, DD, 31, 0, nullptr, nullptr, nullptr);

    // 3. V^T = Wv @ x^T -> (B, D, S) fp8, col-batch-split store  grid 64x8
    gemm_f8<1, f8_t><<<dim3((BB * SS) / 128, DD / 128, 1), 256, 0, stream>>>(
        w8 + 2 * nw, x8, (f8_t*)vt8, DD, BB * SS, DD, 0, 0, 0, SS, 11, (long)DD * SS,
        nullptr, nullptr, nullptr);

    // 4. T = exp(mask*scores)-1 (x512, fp8) + row sums of t  grid 16x16x4
    gemm_f8<2, f8_t><<<dim3(SS / 128, SS / 128, BB), 256, 0, stream>>>(
        qk8, qk8 + nx, (f8_t*)t8, SS, SS, DD, (long)SS * DD, (long)SS * DD, (long)SS * SS,
        SS, 31, 0, qmask, rs, nullptr);

    // 5. out = (T@V * 2^-9 + colsumV) / (2048 + rowsum_t), fp32  grid 8x16x4
    gemm_f8<3, float><<<dim3(DD / 128, SS / 128, BB), 256, 0, stream>>>(
        t8, vt8, out, SS, DD, SS, (long)SS * SS, (long)DD * SS, (long)SS * DD,
        DD, 31, 0, nullptr, rs, colsum);
}

// Round 7
// 225.461 us; speedup vs baseline: 1.0338x; 1.0338x over previous
//
#include <hip/hip_runtime.h>
#include <hip/hip_bf16.h>

// Problem constants (B=4, S=2048, D=1024, fp32 in/out)
#define BB 4
#define SS 2048
#define DD 1024

using f32x4  = __attribute__((ext_vector_type(4))) float;
using f32x16 = __attribute__((ext_vector_type(16))) float;
using i32x4  = __attribute__((ext_vector_type(4))) int;
using i32x8  = __attribute__((ext_vector_type(8))) int;

struct f8_t { unsigned char b; };

// async global->LDS, 16B per lane. LDS dest = wave-uniform base + lane*16.
__device__ __forceinline__ void gld16(const void* g, void* l) {
    __builtin_amdgcn_global_load_lds(
        (const __attribute__((address_space(1))) void*)(g),
        (__attribute__((address_space(3))) void*)(l),
        16, 0, 0);
}

__device__ __forceinline__ void store1(float* p, float v) { *p = v; }
__device__ __forceinline__ void store1(f8_t* p, float v)  {
    p->b = (unsigned char)(__builtin_amdgcn_cvt_pk_fp8_f32(v, v, 0, false) & 0xff);
}

// ---------------------------------------------------------------------------
// Dispatch 1: Wq,Wk,Wv -> fp8 contiguous (blocks 0..1535) AND zero the
// xsum+rs atomic accumulators (block 1536) -- replaces the hipMemsetAsync
// dispatch. n8 = nw/8.
// ---------------------------------------------------------------------------
__global__ void cvt_w_zero(const float* __restrict__ Wq, const float* __restrict__ Wk,
                           const float* __restrict__ Wv, unsigned char* __restrict__ w8,
                           int n8, float* __restrict__ zbuf) {
    if (blockIdx.x == 1536) {           // zero xsum (4096) + rs (8192)
        for (int i = threadIdx.x; i < 12288; i += 256) zbuf[i] = 0.f;
        return;
    }
    int i = blockIdx.x * blockDim.x + threadIdx.x;
    int seg = i / n8;            // wave-uniform (n8 % 256 == 0)
    int j = i - seg * n8;
    const float* src = (seg == 0) ? Wq : (seg == 1) ? Wk : Wv;
    float4 a = ((const float4*)src)[2 * j];
    float4 b = ((const float4*)src)[2 * j + 1];
    int lo = __builtin_amdgcn_cvt_pk_fp8_f32(a.x, a.y, 0, false);
    lo     = __builtin_amdgcn_cvt_pk_fp8_f32(a.z, a.w, lo, true);
    int hi = __builtin_amdgcn_cvt_pk_fp8_f32(b.x, b.y, 0, false);
    hi     = __builtin_amdgcn_cvt_pk_fp8_f32(b.z, b.w, hi, true);
    ((int2*)(w8 + (size_t)seg * n8 * 8))[j] = make_int2(lo, hi);
}

// ---------------------------------------------------------------------------
// Dispatch 2: x fp32 -> fp8(e4m3)  AND  xsum[b][d] = sum_s x[b][s][d] (fp32
// exact -- the output's leading term colsumV/2048 flows through this).
// Reads x ONCE. grid 256: block = (b, 32-row s-chunk).
// ---------------------------------------------------------------------------
__global__ void cvt_x_xsum_kernel(const float* __restrict__ x,
                                  unsigned char* __restrict__ x8,
                                  float* __restrict__ xsum) {
    int b  = blockIdx.x >> 6;
    int s0 = (blockIdx.x & 63) * 32;
    int t  = threadIdx.x;
    int g  = t >> 7;                  // 0..1 : row group (16 rows each)
    int dt = t & 127;
    int d8 = dt * 8;
    const float* xb = x + ((size_t)b * SS + s0 + g * 16) * DD + d8;
    unsigned char* x8b = x8 + ((size_t)b * SS + s0 + g * 16) * DD + d8;

    float a0=0,a1=0,a2=0,a3=0,a4=0,a5=0,a6=0,a7=0;
#pragma unroll 4
    for (int i = 0; i < 16; ++i) {
        float4 u = *(const float4*)(xb + (size_t)i * DD);
        float4 v = *(const float4*)(xb + (size_t)i * DD + 4);
        int lo = __builtin_amdgcn_cvt_pk_fp8_f32(u.x, u.y, 0, false);
        lo     = __builtin_amdgcn_cvt_pk_fp8_f32(u.z, u.w, lo, true);
        int hi = __builtin_amdgcn_cvt_pk_fp8_f32(v.x, v.y, 0, false);
        hi     = __builtin_amdgcn_cvt_pk_fp8_f32(v.z, v.w, hi, true);
        *(int2*)(x8b + (size_t)i * DD) = make_int2(lo, hi);
        a0 += u.x; a1 += u.y; a2 += u.z; a3 += u.w;
        a4 += v.x; a5 += v.y; a6 += v.z; a7 += v.w;
    }
    __shared__ float red[2][128][8];
    float* r = red[g][dt];
    r[0]=a0; r[1]=a1; r[2]=a2; r[3]=a3; r[4]=a4; r[5]=a5; r[6]=a6; r[7]=a7;
    __syncthreads();
    if (t < 128) {
        float* p0 = red[0][t];
        float* p1 = red[1][t];
#pragma unroll
        for (int j = 0; j < 8; ++j)
            atomicAdd(&xsum[b * DD + t * 8 + j], p0[j] + p1[j]);
    }
}

// ---------------------------------------------------------------------------
// colsumV[b][c] = sum_d xsum[b][d] * Wv[c][d]  (one wave per output, exact
// fp32). Runs as virtual blocks inside the fused dispatch.
// ---------------------------------------------------------------------------
__device__ __forceinline__ void colsumv_body(const float* __restrict__ Wv,
                                             const float* __restrict__ xsum,
                                             float* __restrict__ colsum,
                                             int vb, int tid) {
    int idx  = vb * 4 + (tid >> 6);    // 0..4095
    int b    = idx >> 10, c = idx & 1023;
    int lane = tid & 63;
    const float* wr = Wv + (size_t)c * DD;
    const float* xs = xsum + b * DD;
    float acc = 0.f;
#pragma unroll 4
    for (int d = lane; d < DD; d += 64) acc += wr[d] * xs[d];
#pragma unroll
    for (int off = 32; off; off >>= 1) acc += __shfl_xor(acc, off);
    if (lane == 0) colsum[idx] = acc;
}

// ---------------------------------------------------------------------------
// fp8 (e4m3) NT GEMM body via MX-scaled MFMA 32x32x64 -- r3-proven loop
// (empirical optimum of rounds 0-6: BK=128, single-buffered 32KB LDS,
// stage -> vmcnt(0) -> sync -> 2 K-steps x (4 ds_read-frag + 4 MFMA) -> sync;
// latency hidden by 4 co-resident blocks/CU).
// 128x128 tile, 256 threads (4 waves, 2x2), per-wave 64x64 out.
// XOR-8 LDS swizzle on the staging source (T2).
// A/B frag layout (32x32x64 f8f6f4): row/col = lane&31, k-bytes =
//   (lane>>5)*32 + kstep*64. C/D: col = lane&31,
//   row = (reg&3) + 8*(reg>>2) + 4*(lane>>5), reg in [0,16).
// Epilogue modes:
//   0: plain store CT              (QK projection, fp8 out)
//   1: col-batch-split fp8 store   (V^T)
//   2: scores: t=exp(acc*qmask/32)-1; store fp8 512t; atomicAdd row sums of t
//   3: PV: out = (acc + colsumV[d]) / (2048 + rsum[q]), fp32; A-scale 2^-9
// ---------------------------------------------------------------------------
template <int MODE, typename CT>
__device__ __forceinline__ void gemm_body(
    const unsigned char* __restrict__ A, const unsigned char* __restrict__ B,
    CT* __restrict__ C, int K,
    long batchA, long batchB, long batchC,
    int ldc, int col_shift, long cstride,
    const float* __restrict__ qmask, float* __restrict__ rsum,
    const float* __restrict__ colsum,
    int bx, int by, long z, unsigned char* smem) {
    constexpr int BM = 128, BN = 128, BK = 128;
    constexpr int SCALE_A = (MODE == 3) ? 118 : 127;   // 2^-9 un-scales T' = 512 t
    unsigned char* As = smem;            // 16 KB
    unsigned char* Bs = smem + 16384;    // 16 KB

    const int tid  = threadIdx.x;
    const int lane = tid & 63;
    const int wv   = tid >> 6;        // 0..3
    const int l31  = lane & 31;
    const int half = lane >> 5;       // 0..1
    const int hb   = half * 2;        // logical 16B-chunk base within a kstep
    const int wm   = wv >> 1;         // 0..1 : 64-row band
    const int wn   = wv & 1;          // 0..1 : 64-col band

    const int m0 = by * BM;
    const int n0 = bx * BN;
    const unsigned char* Ab = A + z * batchA;
    const unsigned char* Bb = B + z * batchB;

    f32x16 acc[2][2] = {};

#define STAGE(dst, src, kt, j) do {                                           \
        int slot_ = (j) * 256 + tid;                                          \
        int r_ = slot_ >> 3;                                                  \
        int c_ = (slot_ & 7) ^ (r_ & 7);                                      \
        gld16((src) + (size_t)r_ * K + ((kt) + c_ * 16),                      \
              (dst) + (size_t)((j) * 256 + wv * 64) * 16);                    \
    } while (0)
#define RDFRAG(f, base, rr, s) do {                                           \
        int r_ = (rr);                                                        \
        int c0_ = (s) * 4 + hb;                                               \
        const unsigned char* rp_ = (base) + r_ * 128;                         \
        i32x4 q0_ = *(const i32x4*)(rp_ + ((c0_ ^ (r_ & 7)) * 16));           \
        i32x4 q1_ = *(const i32x4*)(rp_ + (((c0_ + 1) ^ (r_ & 7)) * 16));     \
        f[0]=q0_[0]; f[1]=q0_[1]; f[2]=q0_[2]; f[3]=q0_[3];                   \
        f[4]=q1_[0]; f[5]=q1_[1]; f[6]=q1_[2]; f[7]=q1_[3];                   \
    } while (0)
#define MFMA(d, a, b) \
        d = __builtin_amdgcn_mfma_scale_f32_32x32x64_f8f6f4(a, b, d, 0, 0, 0, SCALE_A, 0, 127)

    for (int kt = 0; kt < K; kt += BK) {
        const unsigned char* Asrc = Ab + (size_t)m0 * K;
        const unsigned char* Bsrc = Bb + (size_t)n0 * K;
        STAGE(As, Asrc, kt, 0); STAGE(As, Asrc, kt, 1);
        STAGE(As, Asrc, kt, 2); STAGE(As, Asrc, kt, 3);
        STAGE(Bs, Bsrc, kt, 0); STAGE(Bs, Bsrc, kt, 1);
        STAGE(Bs, Bsrc, kt, 2); STAGE(Bs, Bsrc, kt, 3);
        asm volatile("s_waitcnt vmcnt(0)" ::: "memory");
        __syncthreads();

#pragma unroll
        for (int s = 0; s < 2; ++s) {
            i32x8 a0, a1, b0, b1;
            RDFRAG(a0, As, wm * 64 +  0 + l31, s);
            RDFRAG(a1, As, wm * 64 + 32 + l31, s);
            RDFRAG(b0, Bs, wn * 64 +  0 + l31, s);
            RDFRAG(b1, Bs, wn * 64 + 32 + l31, s);
            MFMA(acc[0][0], a0, b0); MFMA(acc[0][1], a0, b1);
            MFMA(acc[1][0], a1, b0); MFMA(acc[1][1], a1, b1);
        }
        __syncthreads();
    }
#undef STAGE
#undef RDFRAG
#undef MFMA

    // ---- epilogue (C/D: col=lane&31, row=(reg&3)+8*(reg>>2)+4*half) --------
    CT* Cb = C + z * batchC;

    if constexpr (MODE == 0) {
#pragma unroll
        for (int mi = 0; mi < 2; ++mi)
#pragma unroll
            for (int ni = 0; ni < 2; ++ni) {
                int colg = n0 + wn * 64 + ni * 32 + l31;
#pragma unroll
                for (int reg = 0; reg < 16; ++reg) {
                    int rowg = m0 + wm * 64 + mi * 32 + (reg & 3) + 8 * (reg >> 2) + 4 * half;
                    store1(Cb + (size_t)rowg * ldc + colg, acc[mi][ni][reg]);
                }
            }
    } else if constexpr (MODE == 1) {
#pragma unroll
        for (int mi = 0; mi < 2; ++mi)
#pragma unroll
            for (int ni = 0; ni < 2; ++ni) {
                int colg = n0 + wn * 64 + ni * 32 + l31;
                int cb   = colg >> col_shift;
                int ccol = colg - (cb << col_shift);
#pragma unroll
                for (int reg = 0; reg < 16; ++reg) {
                    int rowg = m0 + wm * 64 + mi * 32 + (reg & 3) + 8 * (reg >> 2) + 4 * half;
                    store1(Cb + (long)cb * cstride + (size_t)rowg * ldc + ccol, acc[mi][ni][reg]);
                }
            }
    } else if constexpr (MODE == 2) {
        const float* qm = qmask + (z << 11);
        float* rs = rsum + (z << 11);
#pragma unroll
        for (int mi = 0; mi < 2; ++mi) {
#pragma unroll
            for (int reg = 0; reg < 16; ++reg) {
                int rowg = m0 + wm * 64 + mi * 32 + (reg & 3) + 8 * (reg >> 2) + 4 * half;
                float fac = qm[rowg] * 0.03125f;     // q_mask / sqrt(1024)
                float part = 0.f;
#pragma unroll
                for (int ni = 0; ni < 2; ++ni) {
                    int colg = n0 + wn * 64 + ni * 32 + l31;
                    float t = __expf(acc[mi][ni][reg] * fac) - 1.0f;
                    part += t;
                    store1(Cb + (size_t)rowg * ldc + colg, t * 512.0f);
                }
                // reduce over the 32 lanes of this half (they share rowg)
                part += __shfl_xor(part, 1);
                part += __shfl_xor(part, 2);
                part += __shfl_xor(part, 4);
                part += __shfl_xor(part, 8);
                part += __shfl_xor(part, 16);
                if (l31 == 0) atomicAdd(&rs[rowg], part);
            }
        }
    } else {  // MODE == 3
        const float* rs = rsum + (z << 11);
        const float* cs = colsum + (z << 10);
#pragma unroll
        for (int mi = 0; mi < 2; ++mi) {
#pragma unroll
            for (int reg = 0; reg < 16; ++reg) {
                int rowg = m0 + wm * 64 + mi * 32 + (reg & 3) + 8 * (reg >> 2) + 4 * half;
                float inv = 1.0f / (2048.0f + rs[rowg]);
#pragma unroll
                for (int ni = 0; ni < 2; ++ni) {
                    int colg = n0 + wn * 64 + ni * 32 + l31;
                    store1(Cb + (size_t)rowg * ldc + colg, (acc[mi][ni][reg] + cs[colg]) * inv);
                }
            }
        }
    }
}

// ---------------------------------------------------------------------------
// Dispatch 3: FUSED independent mid-stage work in ONE launch (3584 blocks):
//   blocks [0,2048)    : Q = x@Wq^T, K = x@Wk^T   (mode 0, z = blk>>10)
//   blocks [2048,2560) : V^T = Wv @ x^T           (mode 1)
//   blocks [2560,3584) : colsumV (exact fp32 GEMV)
// All three depend only on dispatches 1-2; merging removes 2 launch gaps.
// ---------------------------------------------------------------------------
__global__ __launch_bounds__(256, 4) void fused_qkvc(
    const unsigned char* __restrict__ x8, const unsigned char* __restrict__ w8,
    unsigned char* __restrict__ qk8, unsigned char* __restrict__ vt8,
    const float* __restrict__ Wv, const float* __restrict__ xsum,
    float* __restrict__ colsum) {
    extern __shared__ unsigned char smem[];
    const long nx = (long)BB * SS * DD;
    const long nw = (long)DD * DD;
    int lin = blockIdx.x;
    if (lin < 2048) {
        long z = lin >> 10;
        int r  = lin & 1023;
        gemm_body<0, f8_t>(x8, w8, (f8_t*)qk8, DD, 0, nw, nx, DD, 31, 0,
                           nullptr, nullptr, nullptr, r & 7, r >> 3, z, smem);
    } else if (lin < 2560) {
        int r = lin - 2048;
        gemm_body<1, f8_t>(w8 + 2 * nw, x8, (f8_t*)vt8, DD, 0, 0, 0, SS, 11,
                           (long)DD * SS, nullptr, nullptr, nullptr,
                           r & 63, r >> 6, 0, smem);
    } else {
        colsumv_body(Wv, xsum, colsum, lin - 2560, threadIdx.x);
    }
}

// Dispatches 4 & 5: standalone GEMM wrapper (scores, PV).
template <int MODE, typename CT>
__global__ __launch_bounds__(256, 4) void gemm_k(
    const unsigned char* __restrict__ A, const unsigned char* __restrict__ B,
    CT* __restrict__ C, int K,
    long batchA, long batchB, long batchC,
    int ldc, int col_shift, long cstride,
    const float* __restrict__ qmask, float* __restrict__ rsum,
    const float* __restrict__ colsum) {
    extern __shared__ unsigned char smem[];
    gemm_body<MODE, CT>(A, B, C, K, batchA, batchB, batchC, ldc, col_shift,
                        cstride, qmask, rsum, colsum,
                        blockIdx.x, blockIdx.y, blockIdx.z, smem);
}

// ---------------------------------------------------------------------------
extern "C" void kernel_launch(void* const* d_in, const int* in_sizes, int n_in,
                              void* d_out, int out_size, void* d_ws, size_t ws_size,
                              hipStream_t stream) {
    const float* x     = (const float*)d_in[0];
    const float* Wq    = (const float*)d_in[1];
    const float* Wk    = (const float*)d_in[2];
    const float* Wv    = (const float*)d_in[3];
    const float* qmask = (const float*)d_in[4];
    float* out = (float*)d_out;

    const long nx = (long)BB * SS * DD;   // 8,388,608
    const long nw = (long)DD * DD;        // 1,048,576

    unsigned char* ws  = (unsigned char*)d_ws;
    unsigned char* x8  = ws;                          // x fp8         8.4 MB
    unsigned char* w8  = x8 + nx;                     // Wq,Wk,Wv fp8  3 MB
    unsigned char* qk8 = w8 + 3 * nw;                 // Q,K fp8       16.8 MB
    unsigned char* vt8 = qk8 + 2 * nx;                // V^T fp8 (B,D,S) 8.4 MB
    unsigned char* t8  = vt8 + nx;                    // T = 512(exp-1) fp8 (B,S,S) 16.8 MB
    float* xsum   = (float*)(t8 + (long)BB * SS * SS);// (B,D) 16 KB
    float* rs     = xsum + BB * DD;                   // (B,S) 32 KB  (Σt per row)
    float* colsum = rs + BB * SS;                     // (B,D) 16 KB  (exact)

    // 1. W convert + zero xsum/rs (replaces memset dispatch)
    cvt_w_zero<<<dim3(1537), dim3(256), 0, stream>>>(Wq, Wk, Wv, w8, (int)(nw / 8), xsum);

    // 2. fused x convert + exact xsum (reads x once)
    cvt_x_xsum_kernel<<<dim3(256), dim3(256), 0, stream>>>(x, x8, xsum);

    // 3. fused: QK projections + V^T + colsumV  (one dispatch, 3584 blocks)
    fused_qkvc<<<dim3(3584), dim3(256), 32768, stream>>>(x8, w8, qk8, vt8, Wv, xsum, colsum);

    // 4. T = exp(mask*scores)-1 (x512, fp8) + row sums of t  grid 16x16x4
    gemm_k<2, f8_t><<<dim3(SS / 128, SS / 128, BB), dim3(256), 32768, stream>>>(
        qk8, qk8 + nx, (f8_t*)t8, DD, (long)SS * DD, (long)SS * DD, (long)SS * SS,
        SS, 31, 0, qmask, rs, nullptr);

    // 5. out = (T@V * 2^-9 + colsumV) / (2048 + rowsum_t), fp32  grid 8x16x4
    gemm_k<3, float><<<dim3(DD / 128, SS / 128, BB), dim3(256), 32768, stream>>>(
        t8, vt8, out, SS, (long)SS * SS, (long)DD * SS, (long)SS * DD,
        DD, 31, 0, nullptr, rs, colsum);
}